// Round 1
// baseline (220.736 us; speedup 1.0000x reference)
//
#include <hip/hip_runtime.h>
#include <hip/hip_bf16.h>
#include <stdint.h>

typedef __attribute__((ext_vector_type(8))) short short8;
typedef __attribute__((ext_vector_type(4))) float f32x4;

#define B_ 2
#define T_ 2048
#define D_ 1024
#define H_ 16
#define HD_ 64
#define BT_ 4096
#define NQT 32
#define NKT 32

__device__ __forceinline__ unsigned short f2bf(float f) {
    union { float f; uint32_t u; } v; v.f = f;
    uint32_t u = v.u;
    uint32_t r = (u + 0x7fffu + ((u >> 16) & 1u)) >> 16;
    return (unsigned short)r;
}

__device__ __forceinline__ void gld16(const void* g, void* l) {
    __builtin_amdgcn_global_load_lds((const __attribute__((address_space(1))) void*)g,
                                     (__attribute__((address_space(3))) void*)l, 16, 0, 0);
}

// XOR-swizzle for [row][128B] LDS tiles: spread rows 0..7 across 8 distinct 16B slots
__device__ __forceinline__ int swz(int x) { return x ^ (((x >> 7) & 7) << 4); }

// ---------------- f32 -> bf16 convert ----------------
__global__ __launch_bounds__(256) void cvt_kernel(const float* __restrict__ src,
                                                  unsigned short* __restrict__ dst, int n8) {
    int i = blockIdx.x * 256 + threadIdx.x;
    if (i >= n8) return;
    const float4* s = (const float4*)src + (size_t)i * 2;
    float4 a = s[0], b4 = s[1];
    short8 o;
    o[0] = (short)f2bf(a.x);  o[1] = (short)f2bf(a.y);
    o[2] = (short)f2bf(a.z);  o[3] = (short)f2bf(a.w);
    o[4] = (short)f2bf(b4.x); o[5] = (short)f2bf(b4.y);
    o[6] = (short)f2bf(b4.z); o[7] = (short)f2bf(b4.w);
    *(short8*)(dst + (size_t)i * 8) = o;
}

// ---------------- QKV projection GEMM: Y[m][n] = sum_k X[m][k] W[n][k] + b[n] ----------------
// out written bf16 in [B,H,T,HD] layout
__global__ __launch_bounds__(256) void qkv_gemm(const unsigned short* __restrict__ X,
                                                const unsigned short* __restrict__ W,
                                                const float* __restrict__ bias,
                                                unsigned short* __restrict__ out) {
    __shared__ unsigned short Al[128 * 32];
    __shared__ unsigned short Bl[128 * 32];
    const int K = D_;
    int m0 = blockIdx.x * 128, n0 = blockIdx.y * 128;
    int tid = threadIdx.x, lane = tid & 63, w = tid >> 6;
    int wr = w >> 1, wc = w & 1;

    f32x4 acc[4][4];
#pragma unroll
    for (int i = 0; i < 4; i++)
#pragma unroll
        for (int j = 0; j < 4; j++) acc[i][j] = (f32x4){0.f, 0.f, 0.f, 0.f};

    int srow0 = (lane >> 2);
    int skch = (lane & 3) * 8;

    for (int kt = 0; kt < K / 32; ++kt) {
        int kb = kt * 32;
#pragma unroll
        for (int t = 0; t < 2; ++t) {
            int ins = w * 2 + t;
            int row = ins * 16 + srow0;
            gld16(X + (size_t)(m0 + row) * K + kb + skch, (char*)Al + ins * 1024);
            gld16(W + (size_t)(n0 + row) * K + kb + skch, (char*)Bl + ins * 1024);
        }
        __syncthreads();
        short8 af[4], bf[4];
#pragma unroll
        for (int mi = 0; mi < 4; mi++)
            af[mi] = *(const short8*)(Al + (wr * 64 + mi * 16 + (lane & 15)) * 32 + (lane >> 4) * 8);
#pragma unroll
        for (int ni = 0; ni < 4; ni++)
            bf[ni] = *(const short8*)(Bl + (wc * 64 + ni * 16 + (lane & 15)) * 32 + (lane >> 4) * 8);
#pragma unroll
        for (int mi = 0; mi < 4; mi++)
#pragma unroll
            for (int ni = 0; ni < 4; ni++)
                acc[mi][ni] = __builtin_amdgcn_mfma_f32_16x16x32_bf16(af[mi], bf[ni], acc[mi][ni], 0, 0, 0);
        __syncthreads();
    }

#pragma unroll
    for (int ni = 0; ni < 4; ni++) {
        int n = n0 + wc * 64 + ni * 16 + (lane & 15);
        float bv = bias[n];
        int h = n >> 6, hd = n & 63;
#pragma unroll
        for (int mi = 0; mi < 4; mi++) {
#pragma unroll
            for (int r = 0; r < 4; r++) {
                int m = m0 + wr * 64 + mi * 16 + (lane >> 4) * 4 + r;
                int b = m >> 11, t = m & (T_ - 1);
                out[((size_t)(b * H_ + h) * T_ + t) * HD_ + hd] = f2bf(acc[mi][ni][r] + bv);
            }
        }
    }
}

// ---------------- V transpose [B,H,T,HD] -> [B,H,HD,T] ----------------
__global__ __launch_bounds__(256) void vtrans(const unsigned short* __restrict__ v,
                                              unsigned short* __restrict__ vt) {
    __shared__ unsigned short tile[64][72];
    int t0 = blockIdx.x * 64;
    int bh = blockIdx.y;
    int tid = threadIdx.x;
#pragma unroll
    for (int it = 0; it < 2; ++it) {
        int u = tid + it * 256;
        int row = u >> 3, ch = u & 7;
        short8 d = *(const short8*)(v + ((size_t)bh * T_ + t0 + row) * HD_ + ch * 8);
#pragma unroll
        for (int j = 0; j < 8; j++) tile[row][ch * 8 + j] = (unsigned short)d[j];
    }
    __syncthreads();
#pragma unroll
    for (int it = 0; it < 2; ++it) {
        int u = tid + it * 256;
        int hd = u >> 3, ch = u & 7;
        short8 o;
#pragma unroll
        for (int j = 0; j < 8; j++) o[j] = (short)tile[ch * 8 + j][hd];
        *(short8*)(vt + ((size_t)bh * HD_ + hd) * T_ + t0 + ch * 8) = o;
    }
}

// ---------------- flash attention ----------------
__global__ __launch_bounds__(256) void attn(const unsigned short* __restrict__ q_ws,
                                            const unsigned short* __restrict__ k_ws,
                                            const unsigned short* __restrict__ vt_ws,
                                            const float* __restrict__ qmask,
                                            const float* __restrict__ kmask,
                                            const int* __restrict__ mfp,
                                            float* __restrict__ out) {
    __shared__ unsigned short Kl[64 * 64];   // logical [kv][hd], swizzled
    __shared__ unsigned short Vl[64 * 64];   // logical [hd][kv], swizzled
    __shared__ unsigned short Pl[4 * 16 * 64]; // per-wave [16][64], swizzled

    int bid = blockIdx.x;
    int qt = (NQT - 1) - (bid & (NQT - 1)); // biggest tiles first
    int bh = bid >> 5;
    int b = bh >> 4, h = bh & 15;
    int tid = threadIdx.x, lane = tid & 63, w = tid >> 6;
    int q0 = qt * 64;
    int qrw = q0 + w * 16;

    int mf = mfp[0];
    int nkt = mf ? (qt + 1) : NKT;

    const unsigned short* qp = q_ws + ((size_t)bh * T_ + qrw + (lane & 15)) * HD_ + (lane >> 4) * 8;
    short8 qf0 = *(const short8*)qp;
    short8 qf1 = *(const short8*)(qp + 32);

    f32x4 o[4];
#pragma unroll
    for (int i = 0; i < 4; i++) o[i] = (f32x4){0.f, 0.f, 0.f, 0.f};
    float mrow[4] = {-1e30f, -1e30f, -1e30f, -1e30f};
    float lrow[4] = {0.f, 0.f, 0.f, 0.f};

    // staging source mapping (linear LDS dest <- swizzled global src)
    int x0 = (w * 2) * 1024 + lane * 16;
    int x1 = x0 + 1024;
    int l0 = swz(x0), l1 = swz(x1);
    int r0 = l0 >> 7, e0 = (l0 & 127) >> 1;
    int r1 = l1 >> 7, e1 = (l1 & 127) >> 1;

    for (int kt = 0; kt < nkt; ++kt) {
        int kv0 = kt * 64;
        gld16(k_ws + ((size_t)bh * T_ + kv0 + r0) * HD_ + e0, (char*)Kl + (w * 2) * 1024);
        gld16(k_ws + ((size_t)bh * T_ + kv0 + r1) * HD_ + e1, (char*)Kl + (w * 2 + 1) * 1024);
        gld16(vt_ws + ((size_t)bh * HD_ + r0) * T_ + kv0 + e0, (char*)Vl + (w * 2) * 1024);
        gld16(vt_ws + ((size_t)bh * HD_ + r1) * T_ + kv0 + e1, (char*)Vl + (w * 2 + 1) * 1024);
        __syncthreads();

        // S = Q K^T : rows q=(lane>>4)*4+r, cols kv=(lane&15)+16*nb
        f32x4 s[4];
#pragma unroll
        for (int nb = 0; nb < 4; nb++) {
            int base = (nb * 16 + (lane & 15)) * 128 + (lane >> 4) * 16;
            short8 kf0 = *(const short8*)((const char*)Kl + swz(base));
            short8 kf1 = *(const short8*)((const char*)Kl + swz(base + 64));
            f32x4 z = (f32x4){0.f, 0.f, 0.f, 0.f};
            z = __builtin_amdgcn_mfma_f32_16x16x32_bf16(qf0, kf0, z, 0, 0, 0);
            z = __builtin_amdgcn_mfma_f32_16x16x32_bf16(qf1, kf1, z, 0, 0, 0);
            s[nb] = z;
        }

        float sv[4][4];
        float pm[4] = {-3e30f, -3e30f, -3e30f, -3e30f};
#pragma unroll
        for (int nb = 0; nb < 4; nb++) {
            int col = kv0 + nb * 16 + (lane & 15);
            float kpen = (1.0f - kmask[b * T_ + col]) * -10000.0f;
#pragma unroll
            for (int r = 0; r < 4; r++) {
                int qrow = qrw + (lane >> 4) * 4 + r;
                float x = s[nb][r] * 0.125f + kpen;
                if (mf && col > qrow) x -= 10000.0f;
                sv[nb][r] = x;
                pm[r] = fmaxf(pm[r], x);
            }
        }
#pragma unroll
        for (int r = 0; r < 4; r++) {
#pragma unroll
            for (int m2 = 1; m2 < 16; m2 <<= 1) pm[r] = fmaxf(pm[r], __shfl_xor(pm[r], m2));
        }
        float sc[4], rs[4];
#pragma unroll
        for (int r = 0; r < 4; r++) {
            float mn = fmaxf(mrow[r], pm[r]);
            sc[r] = __expf(mrow[r] - mn);
            mrow[r] = mn;
            rs[r] = 0.f;
        }
#pragma unroll
        for (int nb = 0; nb < 4; nb++) {
#pragma unroll
            for (int r = 0; r < 4; r++) {
                float p = __expf(sv[nb][r] - mrow[r]);
                rs[r] += p;
                int prow = (lane >> 4) * 4 + r;
                int pbyte = prow * 128 + (nb * 16 + (lane & 15)) * 2;
                *(unsigned short*)((char*)Pl + w * 2048 + swz(pbyte)) = f2bf(p);
            }
        }
#pragma unroll
        for (int r = 0; r < 4; r++) {
#pragma unroll
            for (int m2 = 1; m2 < 16; m2 <<= 1) rs[r] += __shfl_xor(rs[r], m2);
            lrow[r] = lrow[r] * sc[r] + rs[r];
        }
#pragma unroll
        for (int nb = 0; nb < 4; nb++)
#pragma unroll
            for (int r = 0; r < 4; r++) o[nb][r] *= sc[r];

        // PV: O[q][hd] += P[q][kv] V[kv][hd]
        int pb = (lane & 15) * 128 + (lane >> 4) * 16;
        short8 pf0 = *(const short8*)((const char*)Pl + w * 2048 + swz(pb));
        short8 pf1 = *(const short8*)((const char*)Pl + w * 2048 + swz(pb + 64));
#pragma unroll
        for (int nb = 0; nb < 4; nb++) {
            int vb = (nb * 16 + (lane & 15)) * 128 + (lane >> 4) * 16;
            short8 vf0 = *(const short8*)((const char*)Vl + swz(vb));
            short8 vf1 = *(const short8*)((const char*)Vl + swz(vb + 64));
            o[nb] = __builtin_amdgcn_mfma_f32_16x16x32_bf16(pf0, vf0, o[nb], 0, 0, 0);
            o[nb] = __builtin_amdgcn_mfma_f32_16x16x32_bf16(pf1, vf1, o[nb], 0, 0, 0);
        }
        __syncthreads();
    }

#pragma unroll
    for (int r = 0; r < 4; r++) {
        int qrow = qrw + (lane >> 4) * 4 + r;
        float inv = qmask[b * T_ + qrow] / lrow[r];
#pragma unroll
        for (int nb = 0; nb < 4; nb++) {
            out[((size_t)(b * T_ + qrow)) * D_ + h * 64 + nb * 16 + (lane & 15)] = o[nb][r] * inv;
        }
    }
}

extern "C" void kernel_launch(void* const* d_in, const int* in_sizes, int n_in,
                              void* d_out, int out_size, void* d_ws, size_t ws_size,
                              hipStream_t stream) {
    const float* xq = (const float*)d_in[0];
    const float* xk = (const float*)d_in[1];
    const float* qmask = (const float*)d_in[2];
    const float* kmask = (const float*)d_in[3];
    const float* Wq = (const float*)d_in[4];
    const float* bq = (const float*)d_in[5];
    const float* Wk = (const float*)d_in[6];
    const float* bk = (const float*)d_in[7];
    const float* Wv = (const float*)d_in[8];
    const float* bv = (const float*)d_in[9];
    const int* mf = (const int*)d_in[10];
    float* out = (float*)d_out;

    char* ws = (char*)d_ws;
    unsigned short* xq_bf = (unsigned short*)(ws);
    unsigned short* xk_bf = (unsigned short*)(ws + (8u << 20));
    unsigned short* wq_bf = (unsigned short*)(ws + (16u << 20));
    unsigned short* wk_bf = (unsigned short*)(ws + (18u << 20));
    unsigned short* wv_bf = (unsigned short*)(ws + (20u << 20));
    unsigned short* q_ws  = (unsigned short*)(ws + (22u << 20));
    unsigned short* k_ws  = (unsigned short*)(ws + (30u << 20));
    unsigned short* v_ws  = (unsigned short*)(ws + (38u << 20));
    unsigned short* vt_ws = (unsigned short*)(ws + (46u << 20));

    cvt_kernel<<<2048, 256, 0, stream>>>(xq, xq_bf, BT_ * D_ / 8);
    cvt_kernel<<<2048, 256, 0, stream>>>(xk, xk_bf, BT_ * D_ / 8);
    cvt_kernel<<<512, 256, 0, stream>>>(Wq, wq_bf, D_ * D_ / 8);
    cvt_kernel<<<512, 256, 0, stream>>>(Wk, wk_bf, D_ * D_ / 8);
    cvt_kernel<<<512, 256, 0, stream>>>(Wv, wv_bf, D_ * D_ / 8);

    dim3 gg(BT_ / 128, D_ / 128);
    qkv_gemm<<<gg, 256, 0, stream>>>(xq_bf, wq_bf, bq, q_ws);
    qkv_gemm<<<gg, 256, 0, stream>>>(xk_bf, wk_bf, bk, k_ws);
    qkv_gemm<<<gg, 256, 0, stream>>>(xk_bf, wv_bf, bv, v_ws);

    vtrans<<<dim3(T_ / 64, B_ * H_), 256, 0, stream>>>(v_ws, vt_ws);

    attn<<<B_ * H_ * NQT, 256, 0, stream>>>(q_ws, k_ws, vt_ws, qmask, kmask, mf, out);
}

// Round 2
// 169.679 us; speedup vs baseline: 1.3009x; 1.3009x over previous
//
#include <hip/hip_runtime.h>
#include <hip/hip_bf16.h>
#include <stdint.h>

typedef __attribute__((ext_vector_type(8))) short short8;
typedef __attribute__((ext_vector_type(4))) short short4_t;
typedef __attribute__((ext_vector_type(4))) float f32x4;

#define B_ 2
#define T_ 2048
#define D_ 1024
#define H_ 16
#define HD_ 64
#define BT_ 4096
#define NKT64 32

__device__ __forceinline__ unsigned short f2bf(float f) {
    union { float f; uint32_t u; } v; v.f = f;
    uint32_t u = v.u;
    uint32_t r = (u + 0x7fffu + ((u >> 16) & 1u)) >> 16;
    return (unsigned short)r;
}

__device__ __forceinline__ void gld16(const void* g, void* l) {
    __builtin_amdgcn_global_load_lds((const __attribute__((address_space(1))) void*)g,
                                     (__attribute__((address_space(3))) void*)l, 16, 0, 0);
}

// XOR-swizzle for [row][128B] LDS tiles
__device__ __forceinline__ int swz(int x) { return x ^ (((x >> 7) & 7) << 4); }

// ---------------- f32 -> bf16 converts (fused launches) ----------------
__global__ __launch_bounds__(256) void cvt2(const float* __restrict__ s0, unsigned short* __restrict__ d0,
                                            const float* __restrict__ s1, unsigned short* __restrict__ d1,
                                            int n8) {
    const float* src = blockIdx.y ? s1 : s0;
    unsigned short* dst = blockIdx.y ? d1 : d0;
    int i = blockIdx.x * 256 + threadIdx.x;
    if (i >= n8) return;
    const float4* s = (const float4*)src + (size_t)i * 2;
    float4 a = s[0], b4 = s[1];
    short8 o;
    o[0] = (short)f2bf(a.x);  o[1] = (short)f2bf(a.y);
    o[2] = (short)f2bf(a.z);  o[3] = (short)f2bf(a.w);
    o[4] = (short)f2bf(b4.x); o[5] = (short)f2bf(b4.y);
    o[6] = (short)f2bf(b4.z); o[7] = (short)f2bf(b4.w);
    *(short8*)(dst + (size_t)i * 8) = o;
}

__global__ __launch_bounds__(256) void cvt3(const float* __restrict__ s0, unsigned short* __restrict__ d0,
                                            const float* __restrict__ s1, unsigned short* __restrict__ d1,
                                            const float* __restrict__ s2, unsigned short* __restrict__ d2,
                                            int n8) {
    const float* src = blockIdx.y == 0 ? s0 : (blockIdx.y == 1 ? s1 : s2);
    unsigned short* dst = blockIdx.y == 0 ? d0 : (blockIdx.y == 1 ? d1 : d2);
    int i = blockIdx.x * 256 + threadIdx.x;
    if (i >= n8) return;
    const float4* s = (const float4*)src + (size_t)i * 2;
    float4 a = s[0], b4 = s[1];
    short8 o;
    o[0] = (short)f2bf(a.x);  o[1] = (short)f2bf(a.y);
    o[2] = (short)f2bf(a.z);  o[3] = (short)f2bf(a.w);
    o[4] = (short)f2bf(b4.x); o[5] = (short)f2bf(b4.y);
    o[6] = (short)f2bf(b4.z); o[7] = (short)f2bf(b4.w);
    *(short8*)(dst + (size_t)i * 8) = o;
}

// ---------------- fused QKV projection GEMM ----------------
// z=0: Q -> q_ws [bh][t][hd]; z=1: K -> k_ws [bh][t][hd];
// z=2: V -> v8_ws [bh][t>>3][hd][t&7] (8-t-blocked so attn reads 16B contiguous along t)
__global__ __launch_bounds__(256) void qkv_gemm_fused(const unsigned short* __restrict__ xq,
                                                      const unsigned short* __restrict__ xk,
                                                      const unsigned short* __restrict__ wq,
                                                      const unsigned short* __restrict__ wk,
                                                      const unsigned short* __restrict__ wv,
                                                      const float* __restrict__ bq,
                                                      const float* __restrict__ bk,
                                                      const float* __restrict__ bv,
                                                      unsigned short* __restrict__ q_ws,
                                                      unsigned short* __restrict__ k_ws,
                                                      unsigned short* __restrict__ v8_ws) {
    __shared__ unsigned short Al[128 * 32];
    __shared__ unsigned short Bl[128 * 32];
    const int K = D_;
    int z = blockIdx.z;
    const unsigned short* X = (z == 0) ? xq : xk;
    const unsigned short* W = (z == 0) ? wq : (z == 1 ? wk : wv);
    const float* bias = (z == 0) ? bq : (z == 1 ? bk : bv);

    int m0 = blockIdx.x * 128, n0 = blockIdx.y * 128;
    int tid = threadIdx.x, lane = tid & 63, w = tid >> 6;
    int wr = w >> 1, wc = w & 1;

    f32x4 acc[4][4];
#pragma unroll
    for (int i = 0; i < 4; i++)
#pragma unroll
        for (int j = 0; j < 4; j++) acc[i][j] = (f32x4){0.f, 0.f, 0.f, 0.f};

    int srow0 = (lane >> 2);
    int skch = (lane & 3) * 8;

    for (int kt = 0; kt < K / 32; ++kt) {
        int kb = kt * 32;
#pragma unroll
        for (int t = 0; t < 2; ++t) {
            int ins = w * 2 + t;
            int row = ins * 16 + srow0;
            gld16(X + (size_t)(m0 + row) * K + kb + skch, (char*)Al + ins * 1024);
            gld16(W + (size_t)(n0 + row) * K + kb + skch, (char*)Bl + ins * 1024);
        }
        __syncthreads();
        short8 af[4], bf[4];
#pragma unroll
        for (int mi = 0; mi < 4; mi++)
            af[mi] = *(const short8*)(Al + (wr * 64 + mi * 16 + (lane & 15)) * 32 + (lane >> 4) * 8);
#pragma unroll
        for (int ni = 0; ni < 4; ni++)
            bf[ni] = *(const short8*)(Bl + (wc * 64 + ni * 16 + (lane & 15)) * 32 + (lane >> 4) * 8);
#pragma unroll
        for (int mi = 0; mi < 4; mi++)
#pragma unroll
            for (int ni = 0; ni < 4; ni++)
                acc[mi][ni] = __builtin_amdgcn_mfma_f32_16x16x32_bf16(af[mi], bf[ni], acc[mi][ni], 0, 0, 0);
        __syncthreads();
    }

    if (z < 2) {
        unsigned short* out = (z == 0) ? q_ws : k_ws;
#pragma unroll
        for (int ni = 0; ni < 4; ni++) {
            int n = n0 + wc * 64 + ni * 16 + (lane & 15);
            float bv2 = bias[n];
            int h = n >> 6, hd = n & 63;
#pragma unroll
            for (int mi = 0; mi < 4; mi++) {
#pragma unroll
                for (int r = 0; r < 4; r++) {
                    int m = m0 + wr * 64 + mi * 16 + (lane >> 4) * 4 + r;
                    int b = m >> 11, t = m & (T_ - 1);
                    out[((size_t)(b * H_ + h) * T_ + t) * HD_ + hd] = f2bf(acc[mi][ni][r] + bv2);
                }
            }
        }
    } else {
#pragma unroll
        for (int ni = 0; ni < 4; ni++) {
            int n = n0 + wc * 64 + ni * 16 + (lane & 15);
            float bv2 = bias[n];
            int h = n >> 6, hd = n & 63;
#pragma unroll
            for (int mi = 0; mi < 4; mi++) {
                int m = m0 + wr * 64 + mi * 16 + (lane >> 4) * 4;
                int b = m >> 11, t = m & (T_ - 1);
                short4_t pk;
#pragma unroll
                for (int r = 0; r < 4; r++) pk[r] = (short)f2bf(acc[mi][ni][r] + bv2);
                *(short4_t*)(v8_ws + (((size_t)(b * H_ + h) * 256 + (t >> 3)) * HD_ + hd) * 8 + (t & 7)) = pk;
            }
        }
    }
}

// ---------------- flash attention: 1 wave/block, 32 q-rows, no barriers ----------------
__global__ __launch_bounds__(64) void attn(const unsigned short* __restrict__ q_ws,
                                           const unsigned short* __restrict__ k_ws,
                                           const unsigned short* __restrict__ v8_ws,
                                           const float* __restrict__ qmask,
                                           const float* __restrict__ kmask,
                                           const int* __restrict__ mfp,
                                           float* __restrict__ out) {
    __shared__ unsigned short Pl[2 * 16 * 64];  // per-wave (1 wave/block), 2 m-blocks

    int bid = blockIdx.x;
    int qt = (T_ / 32 - 1) - (bid >> 5);  // largest tiles first
    int bh = bid & 31;                    // head stride 32 == 0 mod 8 -> head pinned to one XCD
    int b = bh >> 4, h = bh & 15;
    int lane = threadIdx.x;
    int q0 = qt * 32;
    int mf = mfp[0];
    int nkt = mf ? (qt >> 1) + 1 : NKT64;

    short8 qf[2][2];
#pragma unroll
    for (int m = 0; m < 2; m++) {
        const unsigned short* qp = q_ws + ((size_t)bh * T_ + q0 + m * 16 + (lane & 15)) * HD_ + (lane >> 4) * 8;
        qf[m][0] = *(const short8*)qp;
        qf[m][1] = *(const short8*)(qp + 32);
    }

    f32x4 o[2][4];
#pragma unroll
    for (int m = 0; m < 2; m++)
#pragma unroll
        for (int i = 0; i < 4; i++) o[m][i] = (f32x4){0.f, 0.f, 0.f, 0.f};
    float mrow[2][4], lrow[2][4];
#pragma unroll
    for (int m = 0; m < 2; m++)
#pragma unroll
        for (int r = 0; r < 4; r++) { mrow[m][r] = -1e30f; lrow[m][r] = 0.f; }

    for (int kt = 0; kt < nkt; ++kt) {
        int kv0 = kt * 64;

        // S = Q K^T, fragments straight from global (L2-resident per head)
        f32x4 s[2][4];
#pragma unroll
        for (int nb = 0; nb < 4; nb++) {
            const unsigned short* kp = k_ws + ((size_t)bh * T_ + kv0 + nb * 16 + (lane & 15)) * HD_ + (lane >> 4) * 8;
            short8 kf0 = *(const short8*)kp;
            short8 kf1 = *(const short8*)(kp + 32);
#pragma unroll
            for (int m = 0; m < 2; m++) {
                f32x4 zz = (f32x4){0.f, 0.f, 0.f, 0.f};
                zz = __builtin_amdgcn_mfma_f32_16x16x32_bf16(qf[m][0], kf0, zz, 0, 0, 0);
                zz = __builtin_amdgcn_mfma_f32_16x16x32_bf16(qf[m][1], kf1, zz, 0, 0, 0);
                s[m][nb] = zz;
            }
        }

        float kpen[4];
#pragma unroll
        for (int nb = 0; nb < 4; nb++)
            kpen[nb] = (1.0f - kmask[b * T_ + kv0 + nb * 16 + (lane & 15)]) * -10000.0f;

#pragma unroll
        for (int m = 0; m < 2; m++) {
            float pm[4] = {-3e30f, -3e30f, -3e30f, -3e30f};
#pragma unroll
            for (int nb = 0; nb < 4; nb++) {
                int col = kv0 + nb * 16 + (lane & 15);
#pragma unroll
                for (int r = 0; r < 4; r++) {
                    int qrow = q0 + m * 16 + (lane >> 4) * 4 + r;
                    float x = s[m][nb][r] * 0.125f + kpen[nb];
                    if (mf && col > qrow) x -= 10000.0f;
                    s[m][nb][r] = x;
                    pm[r] = fmaxf(pm[r], x);
                }
            }
            float sc[4], rs[4];
#pragma unroll
            for (int r = 0; r < 4; r++) {
#pragma unroll
                for (int m2 = 1; m2 < 16; m2 <<= 1) pm[r] = fmaxf(pm[r], __shfl_xor(pm[r], m2));
                float mn = fmaxf(mrow[m][r], pm[r]);
                sc[r] = __expf(mrow[m][r] - mn);
                mrow[m][r] = mn;
                rs[r] = 0.f;
            }
#pragma unroll
            for (int nb = 0; nb < 4; nb++) {
#pragma unroll
                for (int r = 0; r < 4; r++) {
                    float p = __expf(s[m][nb][r] - mrow[m][r]);
                    rs[r] += p;
                    int prow = (lane >> 4) * 4 + r;
                    int pbyte = prow * 128 + (nb * 16 + (lane & 15)) * 2;
                    *(unsigned short*)((char*)Pl + m * 2048 + swz(pbyte)) = f2bf(p);
                }
            }
#pragma unroll
            for (int r = 0; r < 4; r++) {
#pragma unroll
                for (int m2 = 1; m2 < 16; m2 <<= 1) rs[r] += __shfl_xor(rs[r], m2);
                lrow[m][r] = lrow[m][r] * sc[r] + rs[r];
            }
#pragma unroll
            for (int nb = 0; nb < 4; nb++)
#pragma unroll
                for (int r = 0; r < 4; r++) o[m][nb][r] *= sc[r];
        }

        // PV: O[q][hd] += P[q][kv] V[kv][hd]
        short8 pf[2][2];
#pragma unroll
        for (int m = 0; m < 2; m++) {
            int pb = (lane & 15) * 128 + (lane >> 4) * 16;
            pf[m][0] = *(const short8*)((const char*)Pl + m * 2048 + swz(pb));
            pf[m][1] = *(const short8*)((const char*)Pl + m * 2048 + swz(pb + 64));
        }
        int t0 = kv0 + (lane >> 4) * 8;
#pragma unroll
        for (int nb = 0; nb < 4; nb++) {
            int hd = nb * 16 + (lane & 15);
            short8 vf0 = *(const short8*)(v8_ws + (((size_t)bh * 256 + (t0 >> 3)) * HD_ + hd) * 8);
            short8 vf1 = *(const short8*)(v8_ws + (((size_t)bh * 256 + ((t0 + 32) >> 3)) * HD_ + hd) * 8);
#pragma unroll
            for (int m = 0; m < 2; m++) {
                o[m][nb] = __builtin_amdgcn_mfma_f32_16x16x32_bf16(pf[m][0], vf0, o[m][nb], 0, 0, 0);
                o[m][nb] = __builtin_amdgcn_mfma_f32_16x16x32_bf16(pf[m][1], vf1, o[m][nb], 0, 0, 0);
            }
        }
    }

#pragma unroll
    for (int m = 0; m < 2; m++)
#pragma unroll
        for (int r = 0; r < 4; r++) {
            int qrow = q0 + m * 16 + (lane >> 4) * 4 + r;
            float inv = qmask[b * T_ + qrow] / lrow[m][r];
#pragma unroll
            for (int nb = 0; nb < 4; nb++)
                out[((size_t)(b * T_ + qrow)) * D_ + h * 64 + nb * 16 + (lane & 15)] = o[m][nb][r] * inv;
        }
}

extern "C" void kernel_launch(void* const* d_in, const int* in_sizes, int n_in,
                              void* d_out, int out_size, void* d_ws, size_t ws_size,
                              hipStream_t stream) {
    const float* xq = (const float*)d_in[0];
    const float* xk = (const float*)d_in[1];
    const float* qmask = (const float*)d_in[2];
    const float* kmask = (const float*)d_in[3];
    const float* Wq = (const float*)d_in[4];
    const float* bq = (const float*)d_in[5];
    const float* Wk = (const float*)d_in[6];
    const float* bk = (const float*)d_in[7];
    const float* Wv = (const float*)d_in[8];
    const float* bv = (const float*)d_in[9];
    const int* mf = (const int*)d_in[10];
    float* out = (float*)d_out;

    char* ws = (char*)d_ws;
    unsigned short* xq_bf = (unsigned short*)(ws);
    unsigned short* xk_bf = (unsigned short*)(ws + (8u << 20));
    unsigned short* wq_bf = (unsigned short*)(ws + (16u << 20));
    unsigned short* wk_bf = (unsigned short*)(ws + (18u << 20));
    unsigned short* wv_bf = (unsigned short*)(ws + (20u << 20));
    unsigned short* q_ws  = (unsigned short*)(ws + (22u << 20));
    unsigned short* k_ws  = (unsigned short*)(ws + (30u << 20));
    unsigned short* v8_ws = (unsigned short*)(ws + (38u << 20));

    cvt2<<<dim3(BT_ * D_ / 8 / 256, 2), 256, 0, stream>>>(xq, xq_bf, xk, xk_bf, BT_ * D_ / 8);
    cvt3<<<dim3(D_ * D_ / 8 / 256, 3), 256, 0, stream>>>(Wq, wq_bf, Wk, wk_bf, Wv, wv_bf, D_ * D_ / 8);

    dim3 gg(BT_ / 128, D_ / 128, 3);
    qkv_gemm_fused<<<gg, 256, 0, stream>>>(xq_bf, xk_bf, wq_bf, wk_bf, wv_bf, bq, bk, bv,
                                           q_ws, k_ws, v8_ws);

    attn<<<(T_ / 32) * 32, 64, 0, stream>>>(q_ws, k_ws, v8_ws, qmask, kmask, mf, out);
}

// Round 3
// 158.376 us; speedup vs baseline: 1.3937x; 1.0714x over previous
//
#include <hip/hip_runtime.h>
#include <hip/hip_bf16.h>
#include <stdint.h>

typedef __attribute__((ext_vector_type(8))) short short8;
typedef __attribute__((ext_vector_type(4))) short short4_t;
typedef __attribute__((ext_vector_type(4))) float f32x4;

#define B_ 2
#define T_ 2048
#define D_ 1024
#define H_ 16
#define HD_ 64
#define BT_ 4096
#define NKT64 32

__device__ __forceinline__ unsigned short f2bf(float f) {
    union { float f; uint32_t u; } v; v.f = f;
    uint32_t u = v.u;
    uint32_t r = (u + 0x7fffu + ((u >> 16) & 1u)) >> 16;
    return (unsigned short)r;
}

__device__ __forceinline__ uint32_t pack2(float a, float b) {
    return (uint32_t)f2bf(a) | ((uint32_t)f2bf(b) << 16);
}

__device__ __forceinline__ void gld16(const void* g, void* l) {
    __builtin_amdgcn_global_load_lds((const __attribute__((address_space(1))) void*)g,
                                     (__attribute__((address_space(3))) void*)l, 16, 0, 0);
}

// XOR-swizzle for [row][128B] LDS tiles
__device__ __forceinline__ int swz(int x) { return x ^ (((x >> 7) & 7) << 4); }

// ---------------- f32 -> bf16 converts + kpen precompute ----------------
__global__ __launch_bounds__(256) void cvt2(const float* __restrict__ s0, unsigned short* __restrict__ d0,
                                            const float* __restrict__ s1, unsigned short* __restrict__ d1,
                                            const float* __restrict__ kmask, float* __restrict__ kpen_g,
                                            int n8) {
    int i = blockIdx.x * 256 + threadIdx.x;
    if (blockIdx.y == 2) {
        // kpen[b][t] = (1 - kmask[b][t]) * -10000
        if (i < B_ * T_) kpen_g[i] = (1.0f - kmask[i]) * -10000.0f;
        return;
    }
    const float* src = blockIdx.y ? s1 : s0;
    unsigned short* dst = blockIdx.y ? d1 : d0;
    if (i >= n8) return;
    const float4* s = (const float4*)src + (size_t)i * 2;
    float4 a = s[0], b4 = s[1];
    short8 o;
    o[0] = (short)f2bf(a.x);  o[1] = (short)f2bf(a.y);
    o[2] = (short)f2bf(a.z);  o[3] = (short)f2bf(a.w);
    o[4] = (short)f2bf(b4.x); o[5] = (short)f2bf(b4.y);
    o[6] = (short)f2bf(b4.z); o[7] = (short)f2bf(b4.w);
    *(short8*)(dst + (size_t)i * 8) = o;
}

__global__ __launch_bounds__(256) void cvt3(const float* __restrict__ s0, unsigned short* __restrict__ d0,
                                            const float* __restrict__ s1, unsigned short* __restrict__ d1,
                                            const float* __restrict__ s2, unsigned short* __restrict__ d2,
                                            int n8) {
    const float* src = blockIdx.y == 0 ? s0 : (blockIdx.y == 1 ? s1 : s2);
    unsigned short* dst = blockIdx.y == 0 ? d0 : (blockIdx.y == 1 ? d1 : d2);
    int i = blockIdx.x * 256 + threadIdx.x;
    if (i >= n8) return;
    const float4* s = (const float4*)src + (size_t)i * 2;
    float4 a = s[0], b4 = s[1];
    short8 o;
    o[0] = (short)f2bf(a.x);  o[1] = (short)f2bf(a.y);
    o[2] = (short)f2bf(a.z);  o[3] = (short)f2bf(a.w);
    o[4] = (short)f2bf(b4.x); o[5] = (short)f2bf(b4.y);
    o[6] = (short)f2bf(b4.z); o[7] = (short)f2bf(b4.w);
    *(short8*)(dst + (size_t)i * 8) = o;
}

// ---------------- fused QKV projection GEMM ----------------
// z=0: Q -> q_ws [bh][t][hd]; z=1: K -> k_ws [bh][t][hd];
// z=2: V -> v8_ws [bh][t>>3][hd][t&7]
__global__ __launch_bounds__(256) void qkv_gemm_fused(const unsigned short* __restrict__ xq,
                                                      const unsigned short* __restrict__ xk,
                                                      const unsigned short* __restrict__ wq,
                                                      const unsigned short* __restrict__ wk,
                                                      const unsigned short* __restrict__ wv,
                                                      const float* __restrict__ bq,
                                                      const float* __restrict__ bk,
                                                      const float* __restrict__ bv,
                                                      unsigned short* __restrict__ q_ws,
                                                      unsigned short* __restrict__ k_ws,
                                                      unsigned short* __restrict__ v8_ws) {
    __shared__ unsigned short Al[128 * 32];
    __shared__ unsigned short Bl[128 * 32];
    const int K = D_;
    int z = blockIdx.z;
    const unsigned short* X = (z == 0) ? xq : xk;
    const unsigned short* W = (z == 0) ? wq : (z == 1 ? wk : wv);
    const float* bias = (z == 0) ? bq : (z == 1 ? bk : bv);

    int m0 = blockIdx.x * 128, n0 = blockIdx.y * 128;
    int tid = threadIdx.x, lane = tid & 63, w = tid >> 6;
    int wr = w >> 1, wc = w & 1;

    f32x4 acc[4][4];
#pragma unroll
    for (int i = 0; i < 4; i++)
#pragma unroll
        for (int j = 0; j < 4; j++) acc[i][j] = (f32x4){0.f, 0.f, 0.f, 0.f};

    int srow0 = (lane >> 2);
    int skch = (lane & 3) * 8;

    for (int kt = 0; kt < K / 32; ++kt) {
        int kb = kt * 32;
#pragma unroll
        for (int t = 0; t < 2; ++t) {
            int ins = w * 2 + t;
            int row = ins * 16 + srow0;
            gld16(X + (size_t)(m0 + row) * K + kb + skch, (char*)Al + ins * 1024);
            gld16(W + (size_t)(n0 + row) * K + kb + skch, (char*)Bl + ins * 1024);
        }
        __syncthreads();
        short8 af[4], bf[4];
#pragma unroll
        for (int mi = 0; mi < 4; mi++)
            af[mi] = *(const short8*)(Al + (wr * 64 + mi * 16 + (lane & 15)) * 32 + (lane >> 4) * 8);
#pragma unroll
        for (int ni = 0; ni < 4; ni++)
            bf[ni] = *(const short8*)(Bl + (wc * 64 + ni * 16 + (lane & 15)) * 32 + (lane >> 4) * 8);
#pragma unroll
        for (int mi = 0; mi < 4; mi++)
#pragma unroll
            for (int ni = 0; ni < 4; ni++)
                acc[mi][ni] = __builtin_amdgcn_mfma_f32_16x16x32_bf16(af[mi], bf[ni], acc[mi][ni], 0, 0, 0);
        __syncthreads();
    }

    if (z < 2) {
        unsigned short* outp = (z == 0) ? q_ws : k_ws;
#pragma unroll
        for (int ni = 0; ni < 4; ni++) {
            int n = n0 + wc * 64 + ni * 16 + (lane & 15);
            float bv2 = bias[n];
            int h = n >> 6, hd = n & 63;
#pragma unroll
            for (int mi = 0; mi < 4; mi++) {
#pragma unroll
                for (int r = 0; r < 4; r++) {
                    int m = m0 + wr * 64 + mi * 16 + (lane >> 4) * 4 + r;
                    int b = m >> 11, t = m & (T_ - 1);
                    outp[((size_t)(b * H_ + h) * T_ + t) * HD_ + hd] = f2bf(acc[mi][ni][r] + bv2);
                }
            }
        }
    } else {
#pragma unroll
        for (int ni = 0; ni < 4; ni++) {
            int n = n0 + wc * 64 + ni * 16 + (lane & 15);
            float bv2 = bias[n];
            int h = n >> 6, hd = n & 63;
#pragma unroll
            for (int mi = 0; mi < 4; mi++) {
                int m = m0 + wr * 64 + mi * 16 + (lane >> 4) * 4;
                int b = m >> 11, t = m & (T_ - 1);
                short4_t pk;
#pragma unroll
                for (int r = 0; r < 4; r++) pk[r] = (short)f2bf(acc[mi][ni][r] + bv2);
                *(short4_t*)(v8_ws + (((size_t)(b * H_ + h) * 256 + (t >> 3)) * HD_ + hd) * 8 + (t & 7)) = pk;
            }
        }
    }
}

// ---------------- flash attention: swapped QK^T, 16 q-rows/wave, 2 waves/block ----------------
__global__ __launch_bounds__(128, 4) void attn(const unsigned short* __restrict__ q_ws,
                                               const unsigned short* __restrict__ k_ws,
                                               const unsigned short* __restrict__ v8_ws,
                                               const float* __restrict__ qmask,
                                               const float* __restrict__ kpen_g,
                                               const int* __restrict__ mfp,
                                               float* __restrict__ out) {
    __shared__ char Pl[2 * 2048];  // per-wave [16 q][64 kv] bf16, swizzled

    int w = threadIdx.x >> 6;
    int lane = threadIdx.x & 63;
    int lg = lane >> 4, q = lane & 15;
    int wid = blockIdx.x * 2 + w;
    int qt = 127 - (wid >> 5);          // largest q-tiles first
    int bh = wid & 31;                  // head pinned per-XCD (stride 32 ≡ 0 mod 8)
    int b = bh >> 4, h = bh & 15;
    int q0 = qt * 16;
    int qg = q0 + q;
    int mf = mfp[0];
    int nkt = mf ? (qt >> 2) + 1 : NKT64;
    char* Pw = Pl + w * 2048;

    // Q fragment (B-operand): lane holds q-col = lane&15, hd chunk lg*8
    const unsigned short* qp = q_ws + ((size_t)bh * T_ + qg) * HD_ + lg * 8;
    short8 qf0 = *(const short8*)qp;
    short8 qf1 = *(const short8*)(qp + 32);

    f32x4 o[4];  // o[nbh]: O^T[hd = nbh*16+lg*4+r][q]
#pragma unroll
    for (int i = 0; i < 4; i++) o[i] = (f32x4){0.f, 0.f, 0.f, 0.f};
    float mrow = -1e30f, lrow = 0.f;

    const float* kpenb = kpen_g + b * T_;

    for (int kt = 0; kt < nkt; ++kt) {
        int kv0 = kt * 64;

        // S^T = K Q^T : lane holds S[kv = kv0+nb*16+lg*4+r][q]
        f32x4 s[4];
#pragma unroll
        for (int nb = 0; nb < 4; nb++) {
            const unsigned short* kp = k_ws + ((size_t)bh * T_ + kv0 + nb * 16 + q) * HD_ + lg * 8;
            short8 kf0 = *(const short8*)kp;
            short8 kf1 = *(const short8*)(kp + 32);
            f32x4 z = (f32x4){0.f, 0.f, 0.f, 0.f};
            z = __builtin_amdgcn_mfma_f32_16x16x32_bf16(kf0, qf0, z, 0, 0, 0);
            z = __builtin_amdgcn_mfma_f32_16x16x32_bf16(kf1, qf1, z, 0, 0, 0);
            s[nb] = z;
        }

        // V fragments (A-operand for PV), issued early — independent of softmax
        short8 vf[4][2];
        {
            const unsigned short* vbase = v8_ws + (((size_t)bh * 256 + (kv0 >> 3) + lg) * 64 + q) * 8;
#pragma unroll
            for (int nbh = 0; nbh < 4; nbh++) {
                vf[nbh][0] = *(const short8*)(vbase + nbh * 128);
                vf[nbh][1] = *(const short8*)(vbase + nbh * 128 + 4 * 512);
            }
        }

        // kpen gather: one float4 per nb
        f32x4 kp4[4];
#pragma unroll
        for (int nb = 0; nb < 4; nb++)
            kp4[nb] = *(const f32x4*)(kpenb + kv0 + nb * 16 + lg * 4);

        bool diag = mf && (kv0 + 63 > q0);
        float x[4][4];
#pragma unroll
        for (int nb = 0; nb < 4; nb++) {
#pragma unroll
            for (int r = 0; r < 4; r++) {
                float v = s[nb][r] * 0.125f + kp4[nb][r];
                if (diag) {
                    int kvg = kv0 + nb * 16 + lg * 4 + r;
                    v = (kvg > qg) ? v - 10000.0f : v;
                }
                x[nb][r] = v;
            }
        }
        // row max: in-lane tree + 2 shfl
        float xm = fmaxf(fmaxf(fmaxf(fmaxf(x[0][0], x[0][1]), fmaxf(x[0][2], x[0][3])),
                               fmaxf(fmaxf(x[1][0], x[1][1]), fmaxf(x[1][2], x[1][3]))),
                         fmaxf(fmaxf(fmaxf(x[2][0], x[2][1]), fmaxf(x[2][2], x[2][3])),
                               fmaxf(fmaxf(x[3][0], x[3][1]), fmaxf(x[3][2], x[3][3]))));
        xm = fmaxf(xm, __shfl_xor(xm, 16));
        xm = fmaxf(xm, __shfl_xor(xm, 32));
        float mn = fmaxf(mrow, xm);
        float sc = __expf(mrow - mn);
        mrow = mn;

        float p[4][4];
#pragma unroll
        for (int nb = 0; nb < 4; nb++)
#pragma unroll
            for (int r = 0; r < 4; r++) p[nb][r] = __expf(x[nb][r] - mn);

        float rs = ((p[0][0] + p[0][1]) + (p[0][2] + p[0][3])) + ((p[1][0] + p[1][1]) + (p[1][2] + p[1][3]))
                 + ((p[2][0] + p[2][1]) + (p[2][2] + p[2][3])) + ((p[3][0] + p[3][1]) + (p[3][2] + p[3][3]));
        rs += __shfl_xor(rs, 16);
        rs += __shfl_xor(rs, 32);
        lrow = lrow * sc + rs;

#pragma unroll
        for (int nbh = 0; nbh < 4; nbh++)
#pragma unroll
            for (int r = 0; r < 4; r++) o[nbh][r] *= sc;

        // P -> LDS [q][kv] bf16 (swizzled), 4 x ds_write_b64
#pragma unroll
        for (int nb = 0; nb < 4; nb++) {
            uint2 ww;
            ww.x = pack2(p[nb][0], p[nb][1]);
            ww.y = pack2(p[nb][2], p[nb][3]);
            *(uint2*)(Pw + swz(q * 128 + nb * 32 + lg * 8)) = ww;
        }

        // P fragments (B-operand): lane reads row q, kv chunk f*32 + lg*8
        short8 pf0 = *(const short8*)(Pw + swz(q * 128 + lg * 16));
        short8 pf1 = *(const short8*)(Pw + swz(q * 128 + 64 + lg * 16));

#pragma unroll
        for (int nbh = 0; nbh < 4; nbh++) {
            o[nbh] = __builtin_amdgcn_mfma_f32_16x16x32_bf16(vf[nbh][0], pf0, o[nbh], 0, 0, 0);
            o[nbh] = __builtin_amdgcn_mfma_f32_16x16x32_bf16(vf[nbh][1], pf1, o[nbh], 0, 0, 0);
        }
    }

    float inv = qmask[b * T_ + qg] / lrow;
    float* op = out + ((size_t)(b * T_ + qg)) * D_ + h * 64 + lg * 4;
#pragma unroll
    for (int nbh = 0; nbh < 4; nbh++) {
        f32x4 ov;
#pragma unroll
        for (int r = 0; r < 4; r++) ov[r] = o[nbh][r] * inv;
        *(f32x4*)(op + nbh * 16) = ov;
    }
}

extern "C" void kernel_launch(void* const* d_in, const int* in_sizes, int n_in,
                              void* d_out, int out_size, void* d_ws, size_t ws_size,
                              hipStream_t stream) {
    const float* xq = (const float*)d_in[0];
    const float* xk = (const float*)d_in[1];
    const float* qmask = (const float*)d_in[2];
    const float* kmask = (const float*)d_in[3];
    const float* Wq = (const float*)d_in[4];
    const float* bq = (const float*)d_in[5];
    const float* Wk = (const float*)d_in[6];
    const float* bk = (const float*)d_in[7];
    const float* Wv = (const float*)d_in[8];
    const float* bv = (const float*)d_in[9];
    const int* mf = (const int*)d_in[10];
    float* out = (float*)d_out;

    char* ws = (char*)d_ws;
    unsigned short* xq_bf = (unsigned short*)(ws);
    unsigned short* xk_bf = (unsigned short*)(ws + (8u << 20));
    unsigned short* wq_bf = (unsigned short*)(ws + (16u << 20));
    unsigned short* wk_bf = (unsigned short*)(ws + (18u << 20));
    unsigned short* wv_bf = (unsigned short*)(ws + (20u << 20));
    unsigned short* q_ws  = (unsigned short*)(ws + (22u << 20));
    unsigned short* k_ws  = (unsigned short*)(ws + (30u << 20));
    unsigned short* v8_ws = (unsigned short*)(ws + (38u << 20));
    float* kpen_g         = (float*)(ws + (46u << 20));

    cvt2<<<dim3(BT_ * D_ / 8 / 256, 3), 256, 0, stream>>>(xq, xq_bf, xk, xk_bf, kmask, kpen_g, BT_ * D_ / 8);
    cvt3<<<dim3(D_ * D_ / 8 / 256, 3), 256, 0, stream>>>(Wq, wq_bf, Wk, wk_bf, Wv, wv_bf, D_ * D_ / 8);

    dim3 gg(BT_ / 128, D_ / 128, 3);
    qkv_gemm_fused<<<gg, 256, 0, stream>>>(xq_bf, xk_bf, wq_bf, wk_bf, wv_bf, bq, bk, bv,
                                           q_ws, k_ws, v8_ws);

    attn<<<(T_ / 16) * 32 / 2, 128, 0, stream>>>(q_ws, k_ws, v8_ws, qmask, kpen_g, mf, out);
}

// Round 4
// 137.031 us; speedup vs baseline: 1.6108x; 1.1558x over previous
//
#include <hip/hip_runtime.h>
#include <hip/hip_bf16.h>
#include <stdint.h>

typedef __attribute__((ext_vector_type(8))) short short8;
typedef __attribute__((ext_vector_type(4))) short short4_t;
typedef __attribute__((ext_vector_type(4))) float f32x4;

#define B_ 2
#define T_ 2048
#define D_ 1024
#define H_ 16
#define HD_ 64
#define BT_ 4096
#define NKT64 32

__device__ __forceinline__ unsigned short f2bf(float f) {
    union { float f; uint32_t u; } v; v.f = f;
    uint32_t u = v.u;
    uint32_t r = (u + 0x7fffu + ((u >> 16) & 1u)) >> 16;
    return (unsigned short)r;
}

__device__ __forceinline__ uint32_t pack2(float a, float b) {
    return (uint32_t)f2bf(a) | ((uint32_t)f2bf(b) << 16);
}

__device__ __forceinline__ void gld16(const void* g, void* l) {
    __builtin_amdgcn_global_load_lds((const __attribute__((address_space(1))) void*)g,
                                     (__attribute__((address_space(3))) void*)l, 16, 0, 0);
}

// XOR-swizzle for [row][128B] LDS tiles
__device__ __forceinline__ int swz(int x) { return x ^ (((x >> 7) & 7) << 4); }

// ---------------- f32 -> bf16 converts + kpen precompute ----------------
__global__ __launch_bounds__(256) void cvt2(const float* __restrict__ s0, unsigned short* __restrict__ d0,
                                            const float* __restrict__ s1, unsigned short* __restrict__ d1,
                                            const float* __restrict__ kmask, float* __restrict__ kpen_g,
                                            int n8) {
    int i = blockIdx.x * 256 + threadIdx.x;
    if (blockIdx.y == 2) {
        if (i < B_ * T_) kpen_g[i] = (1.0f - kmask[i]) * -10000.0f;
        return;
    }
    const float* src = blockIdx.y ? s1 : s0;
    unsigned short* dst = blockIdx.y ? d1 : d0;
    if (i >= n8) return;
    const float4* s = (const float4*)src + (size_t)i * 2;
    float4 a = s[0], b4 = s[1];
    short8 o;
    o[0] = (short)f2bf(a.x);  o[1] = (short)f2bf(a.y);
    o[2] = (short)f2bf(a.z);  o[3] = (short)f2bf(a.w);
    o[4] = (short)f2bf(b4.x); o[5] = (short)f2bf(b4.y);
    o[6] = (short)f2bf(b4.z); o[7] = (short)f2bf(b4.w);
    *(short8*)(dst + (size_t)i * 8) = o;
}

__global__ __launch_bounds__(256) void cvt3(const float* __restrict__ s0, unsigned short* __restrict__ d0,
                                            const float* __restrict__ s1, unsigned short* __restrict__ d1,
                                            const float* __restrict__ s2, unsigned short* __restrict__ d2,
                                            int n8) {
    const float* src = blockIdx.y == 0 ? s0 : (blockIdx.y == 1 ? s1 : s2);
    unsigned short* dst = blockIdx.y == 0 ? d0 : (blockIdx.y == 1 ? d1 : d2);
    int i = blockIdx.x * 256 + threadIdx.x;
    if (i >= n8) return;
    const float4* s = (const float4*)src + (size_t)i * 2;
    float4 a = s[0], b4 = s[1];
    short8 o;
    o[0] = (short)f2bf(a.x);  o[1] = (short)f2bf(a.y);
    o[2] = (short)f2bf(a.z);  o[3] = (short)f2bf(a.w);
    o[4] = (short)f2bf(b4.x); o[5] = (short)f2bf(b4.y);
    o[6] = (short)f2bf(b4.z); o[7] = (short)f2bf(b4.w);
    *(short8*)(dst + (size_t)i * 8) = o;
}

// ---------------- fused QKV projection GEMM ----------------
__global__ __launch_bounds__(256) void qkv_gemm_fused(const unsigned short* __restrict__ xq,
                                                      const unsigned short* __restrict__ xk,
                                                      const unsigned short* __restrict__ wq,
                                                      const unsigned short* __restrict__ wk,
                                                      const unsigned short* __restrict__ wv,
                                                      const float* __restrict__ bq,
                                                      const float* __restrict__ bk,
                                                      const float* __restrict__ bv,
                                                      unsigned short* __restrict__ q_ws,
                                                      unsigned short* __restrict__ k_ws,
                                                      unsigned short* __restrict__ v8_ws) {
    __shared__ unsigned short Al[128 * 32];
    __shared__ unsigned short Bl[128 * 32];
    const int K = D_;
    int z = blockIdx.z;
    const unsigned short* X = (z == 0) ? xq : xk;
    const unsigned short* W = (z == 0) ? wq : (z == 1 ? wk : wv);
    const float* bias = (z == 0) ? bq : (z == 1 ? bk : bv);

    int m0 = blockIdx.x * 128, n0 = blockIdx.y * 128;
    int tid = threadIdx.x, lane = tid & 63, w = tid >> 6;
    int wr = w >> 1, wc = w & 1;

    f32x4 acc[4][4];
#pragma unroll
    for (int i = 0; i < 4; i++)
#pragma unroll
        for (int j = 0; j < 4; j++) acc[i][j] = (f32x4){0.f, 0.f, 0.f, 0.f};

    int srow0 = (lane >> 2);
    int skch = (lane & 3) * 8;

    for (int kt = 0; kt < K / 32; ++kt) {
        int kb = kt * 32;
#pragma unroll
        for (int t = 0; t < 2; ++t) {
            int ins = w * 2 + t;
            int row = ins * 16 + srow0;
            gld16(X + (size_t)(m0 + row) * K + kb + skch, (char*)Al + ins * 1024);
            gld16(W + (size_t)(n0 + row) * K + kb + skch, (char*)Bl + ins * 1024);
        }
        __syncthreads();
        short8 af[4], bf[4];
#pragma unroll
        for (int mi = 0; mi < 4; mi++)
            af[mi] = *(const short8*)(Al + (wr * 64 + mi * 16 + (lane & 15)) * 32 + (lane >> 4) * 8);
#pragma unroll
        for (int ni = 0; ni < 4; ni++)
            bf[ni] = *(const short8*)(Bl + (wc * 64 + ni * 16 + (lane & 15)) * 32 + (lane >> 4) * 8);
#pragma unroll
        for (int mi = 0; mi < 4; mi++)
#pragma unroll
            for (int ni = 0; ni < 4; ni++)
                acc[mi][ni] = __builtin_amdgcn_mfma_f32_16x16x32_bf16(af[mi], bf[ni], acc[mi][ni], 0, 0, 0);
        __syncthreads();
    }

    if (z < 2) {
        unsigned short* outp = (z == 0) ? q_ws : k_ws;
#pragma unroll
        for (int ni = 0; ni < 4; ni++) {
            int n = n0 + wc * 64 + ni * 16 + (lane & 15);
            float bv2 = bias[n];
            int h = n >> 6, hd = n & 63;
#pragma unroll
            for (int mi = 0; mi < 4; mi++) {
#pragma unroll
                for (int r = 0; r < 4; r++) {
                    int m = m0 + wr * 64 + mi * 16 + (lane >> 4) * 4 + r;
                    int b = m >> 11, t = m & (T_ - 1);
                    outp[((size_t)(b * H_ + h) * T_ + t) * HD_ + hd] = f2bf(acc[mi][ni][r] + bv2);
                }
            }
        }
    } else {
#pragma unroll
        for (int ni = 0; ni < 4; ni++) {
            int n = n0 + wc * 64 + ni * 16 + (lane & 15);
            float bv2 = bias[n];
            int h = n >> 6, hd = n & 63;
#pragma unroll
            for (int mi = 0; mi < 4; mi++) {
                int m = m0 + wr * 64 + mi * 16 + (lane >> 4) * 4;
                int b = m >> 11, t = m & (T_ - 1);
                short4_t pk;
#pragma unroll
                for (int r = 0; r < 4; r++) pk[r] = (short)f2bf(acc[mi][ni][r] + bv2);
                *(short4_t*)(v8_ws + (((size_t)(b * H_ + h) * 256 + (t >> 3)) * HD_ + hd) * 8 + (t & 7)) = pk;
            }
        }
    }
}

// ---------------- flash attention: 32 q-rows/wave, K reg-double-buffer, no barriers ----------------
__global__ __launch_bounds__(128, 2) void attn(const unsigned short* __restrict__ q_ws,
                                               const unsigned short* __restrict__ k_ws,
                                               const unsigned short* __restrict__ v8_ws,
                                               const float* __restrict__ qmask,
                                               const float* __restrict__ kpen_g,
                                               const int* __restrict__ mfp,
                                               float* __restrict__ out) {
    __shared__ char Pl[2 * 2 * 2048];  // [wave][m][16q][64kv] bf16, swizzled

    int w = threadIdx.x >> 6;
    int lane = threadIdx.x & 63;
    int lg = lane >> 4, q = lane & 15;
    int wid = blockIdx.x * 2 + w;
    int qt = 63 - (wid >> 5);            // 32-row q-tiles, largest first
    int bh = wid & 31;                   // head pinned per-XCD
    int b = bh >> 4, h = bh & 15;
    int q0 = qt * 32;
    int mf = mfp[0];
    int nkt = mf ? (qt >> 1) + 1 : NKT64;
    char* Pw = Pl + w * 4096;

    // Q fragments (B-operand), 2 m-subtiles
    short8 qf[2][2];
#pragma unroll
    for (int m = 0; m < 2; m++) {
        const unsigned short* qp = q_ws + ((size_t)bh * T_ + q0 + m * 16 + q) * HD_ + lg * 8;
        qf[m][0] = *(const short8*)qp;
        qf[m][1] = *(const short8*)(qp + 32);
    }

    f32x4 o[2][4];
#pragma unroll
    for (int m = 0; m < 2; m++)
#pragma unroll
        for (int i = 0; i < 4; i++) o[m][i] = (f32x4){0.f, 0.f, 0.f, 0.f};
    float mrow[2] = {-1e30f, -1e30f};
    float lrow[2] = {0.f, 0.f};

    const float* kpenb = kpen_g + b * T_;

    auto loadK = [&](int kv0, short8 (&ka)[4], short8 (&kb)[4]) {
#pragma unroll
        for (int nb = 0; nb < 4; nb++) {
            const unsigned short* kp = k_ws + ((size_t)bh * T_ + kv0 + nb * 16 + q) * HD_ + lg * 8;
            ka[nb] = *(const short8*)kp;
            kb[nb] = *(const short8*)(kp + 32);
        }
    };

    auto tile_step = [&](int kv0, const short8 (&ka)[4], const short8 (&kb)[4]) {
        // S^T = K Q^T : lane holds S[kv0 + nb*16 + lg*4 + r][q], per m
        f32x4 s[2][4];
        __builtin_amdgcn_s_setprio(1);
#pragma unroll
        for (int nb = 0; nb < 4; nb++) {
#pragma unroll
            for (int m = 0; m < 2; m++) {
                f32x4 z = (f32x4){0.f, 0.f, 0.f, 0.f};
                z = __builtin_amdgcn_mfma_f32_16x16x32_bf16(ka[nb], qf[m][0], z, 0, 0, 0);
                z = __builtin_amdgcn_mfma_f32_16x16x32_bf16(kb[nb], qf[m][1], z, 0, 0, 0);
                s[m][nb] = z;
            }
        }
        __builtin_amdgcn_s_setprio(0);

        // V fragments (A-operand), issued early — latency hides under softmax
        short8 vf[4][2];
        const unsigned short* vbase = v8_ws + (((size_t)bh * 256 + (kv0 >> 3) + lg) * 64 + q) * 8;
#pragma unroll
        for (int nbh = 0; nbh < 4; nbh++) {
            vf[nbh][0] = *(const short8*)(vbase + nbh * 128);
            vf[nbh][1] = *(const short8*)(vbase + nbh * 128 + 2048);
        }

        f32x4 kp4[4];
#pragma unroll
        for (int nb = 0; nb < 4; nb++)
            kp4[nb] = *(const f32x4*)(kpenb + kv0 + nb * 16 + lg * 4);

        bool diag = mf && (kv0 + 63 > q0);
        float sc[2];
#pragma unroll
        for (int m = 0; m < 2; m++) {
            int qg = q0 + m * 16 + q;
#pragma unroll
            for (int nb = 0; nb < 4; nb++) {
#pragma unroll
                for (int r = 0; r < 4; r++) {
                    float v = s[m][nb][r] * 0.125f + kp4[nb][r];
                    if (diag) {
                        int kvg = kv0 + nb * 16 + lg * 4 + r;
                        v = (kvg > qg) ? v - 10000.0f : v;
                    }
                    s[m][nb][r] = v;
                }
            }
            float xm = fmaxf(
                fmaxf(fmaxf(fmaxf(s[m][0][0], s[m][0][1]), fmaxf(s[m][0][2], s[m][0][3])),
                      fmaxf(fmaxf(s[m][1][0], s[m][1][1]), fmaxf(s[m][1][2], s[m][1][3]))),
                fmaxf(fmaxf(fmaxf(s[m][2][0], s[m][2][1]), fmaxf(s[m][2][2], s[m][2][3])),
                      fmaxf(fmaxf(s[m][3][0], s[m][3][1]), fmaxf(s[m][3][2], s[m][3][3]))));
            xm = fmaxf(xm, __shfl_xor(xm, 16));
            xm = fmaxf(xm, __shfl_xor(xm, 32));
            float mn = fmaxf(mrow[m], xm);
            sc[m] = __expf(mrow[m] - mn);
            mrow[m] = mn;

#pragma unroll
            for (int nb = 0; nb < 4; nb++)
#pragma unroll
                for (int r = 0; r < 4; r++) s[m][nb][r] = __expf(s[m][nb][r] - mn);

            float rs = ((s[m][0][0] + s[m][0][1]) + (s[m][0][2] + s[m][0][3]))
                     + ((s[m][1][0] + s[m][1][1]) + (s[m][1][2] + s[m][1][3]))
                     + ((s[m][2][0] + s[m][2][1]) + (s[m][2][2] + s[m][2][3]))
                     + ((s[m][3][0] + s[m][3][1]) + (s[m][3][2] + s[m][3][3]));
            rs += __shfl_xor(rs, 16);
            rs += __shfl_xor(rs, 32);
            lrow[m] = lrow[m] * sc[m] + rs;

#pragma unroll
            for (int nbh = 0; nbh < 4; nbh++)
#pragma unroll
                for (int r = 0; r < 4; r++) o[m][nbh][r] *= sc[m];

            // P -> LDS [q][kv] bf16 (swizzled)
#pragma unroll
            for (int nb = 0; nb < 4; nb++) {
                uint2 ww;
                ww.x = pack2(s[m][nb][0], s[m][nb][1]);
                ww.y = pack2(s[m][nb][2], s[m][nb][3]);
                *(uint2*)(Pw + m * 2048 + swz(q * 128 + nb * 32 + lg * 8)) = ww;
            }
        }

        short8 pf[2][2];
#pragma unroll
        for (int m = 0; m < 2; m++) {
            pf[m][0] = *(const short8*)(Pw + m * 2048 + swz(q * 128 + lg * 16));
            pf[m][1] = *(const short8*)(Pw + m * 2048 + swz(q * 128 + 64 + lg * 16));
        }

        __builtin_amdgcn_s_setprio(1);
#pragma unroll
        for (int nbh = 0; nbh < 4; nbh++) {
#pragma unroll
            for (int m = 0; m < 2; m++) {
                o[m][nbh] = __builtin_amdgcn_mfma_f32_16x16x32_bf16(vf[nbh][0], pf[m][0], o[m][nbh], 0, 0, 0);
                o[m][nbh] = __builtin_amdgcn_mfma_f32_16x16x32_bf16(vf[nbh][1], pf[m][1], o[m][nbh], 0, 0, 0);
            }
        }
        __builtin_amdgcn_s_setprio(0);
    };

    // K register double-buffer, manual ping-pong (static indexing only)
    short8 kA0[4], kA1[4], kB0[4], kB1[4];
    loadK(0, kA0, kA1);
    int kt = 0;
    while (true) {
        int kvn = (kt + 1 < nkt ? kt + 1 : kt) * 64;
        loadK(kvn, kB0, kB1);
        tile_step(kt * 64, kA0, kA1);
        if (++kt >= nkt) break;
        int kvn2 = (kt + 1 < nkt ? kt + 1 : kt) * 64;
        loadK(kvn2, kA0, kA1);
        tile_step(kt * 64, kB0, kB1);
        if (++kt >= nkt) break;
    }

#pragma unroll
    for (int m = 0; m < 2; m++) {
        int qg = q0 + m * 16 + q;
        float inv = qmask[b * T_ + qg] / lrow[m];
        float* op = out + ((size_t)(b * T_ + qg)) * D_ + h * 64 + lg * 4;
#pragma unroll
        for (int nbh = 0; nbh < 4; nbh++) {
            f32x4 ov;
#pragma unroll
            for (int r = 0; r < 4; r++) ov[r] = o[m][nbh][r] * inv;
            *(f32x4*)(op + nbh * 16) = ov;
        }
    }
}

extern "C" void kernel_launch(void* const* d_in, const int* in_sizes, int n_in,
                              void* d_out, int out_size, void* d_ws, size_t ws_size,
                              hipStream_t stream) {
    const float* xq = (const float*)d_in[0];
    const float* xk = (const float*)d_in[1];
    const float* qmask = (const float*)d_in[2];
    const float* kmask = (const float*)d_in[3];
    const float* Wq = (const float*)d_in[4];
    const float* bq = (const float*)d_in[5];
    const float* Wk = (const float*)d_in[6];
    const float* bk = (const float*)d_in[7];
    const float* Wv = (const float*)d_in[8];
    const float* bv = (const float*)d_in[9];
    const int* mf = (const int*)d_in[10];
    float* out = (float*)d_out;

    char* ws = (char*)d_ws;
    unsigned short* xq_bf = (unsigned short*)(ws);
    unsigned short* xk_bf = (unsigned short*)(ws + (8u << 20));
    unsigned short* wq_bf = (unsigned short*)(ws + (16u << 20));
    unsigned short* wk_bf = (unsigned short*)(ws + (18u << 20));
    unsigned short* wv_bf = (unsigned short*)(ws + (20u << 20));
    unsigned short* q_ws  = (unsigned short*)(ws + (22u << 20));
    unsigned short* k_ws  = (unsigned short*)(ws + (30u << 20));
    unsigned short* v8_ws = (unsigned short*)(ws + (38u << 20));
    float* kpen_g         = (float*)(ws + (46u << 20));

    cvt2<<<dim3(BT_ * D_ / 8 / 256, 3), 256, 0, stream>>>(xq, xq_bf, xk, xk_bf, kmask, kpen_g, BT_ * D_ / 8);
    cvt3<<<dim3(D_ * D_ / 8 / 256, 3), 256, 0, stream>>>(Wq, wq_bf, Wk, wk_bf, Wv, wv_bf, D_ * D_ / 8);

    dim3 gg(BT_ / 128, D_ / 128, 3);
    qkv_gemm_fused<<<gg, 256, 0, stream>>>(xq_bf, xk_bf, wq_bf, wk_bf, wv_bf, bq, bk, bv,
                                           q_ws, k_ws, v8_ws);

    attn<<<1024, 128, 0, stream>>>(q_ws, k_ws, v8_ws, qmask, kpen_g, mf, out);
}